// Round 13
// baseline (107.144 us; speedup 1.0000x reference)
//
#include <hip/hip_runtime.h>
#include <hip/hip_bf16.h>
#include <stdint.h>

// Problem constants
#define NF 4096
#define NS 1024
#define MD 512
#define HD 64
#define DA 96
#define GHID 128

#define L2E 1.44269504f          // log2(e)
#define S2L 1.6986436f           // sqrt(2*log2e)  (LAMBDA_GEO=1)
#define SMAX 12.0f               // static softmax offset
#define NSPLIT 2                 // flash NS splits

typedef unsigned short u16;
typedef __attribute__((ext_vector_type(8))) short bf8v;   // 8 bf16
typedef __attribute__((ext_vector_type(4))) float f4v;

__device__ __forceinline__ u16 f2bf(float f) {
  __hip_bfloat16 h = __float2bfloat16(f);
  return __builtin_bit_cast(u16, h);
}
__device__ __forceinline__ float bf2f(u16 u) {
  union { unsigned u; float f; } v; v.u = ((unsigned)u) << 16; return v.f;
}
__device__ __forceinline__ f4v mfma16(bf8v a, bf8v b, f4v c) {
  return __builtin_amdgcn_mfma_f32_16x16x32_bf16(a, b, c, 0, 0, 0);
}
__device__ __forceinline__ void gld16(const void* g, void* l) {
  __builtin_amdgcn_global_load_lds(
      (const __attribute__((address_space(1))) unsigned int*)g,
      (__attribute__((address_space(3))) unsigned int*)l, 16, 0, 0);
}

// weight pool offsets (bf16 elements)
#define OFF_POSW2 0
#define OFF_FAW   262144
#define OFF_SAW   425984
#define OFF_WQ    819200
#define OFF_WKV   1081344
#define OFF_PLKW2 1605632
#define OFF_SXYW2 1622016
#define OFF_WQG   1638400
#define OFF_WKG   1654784
#define OFF_SATT  1671168
#define TOTW      2457600

// epilogue modes
#define EPI_OUT  0
#define EPI_ROPE 1
#define EPI_VT   2
#define EPI_GEO  3

// ================= L0: convert + ffT + silus + aug pad/cross dims + kk2 =================
// blocks: [0,2401) convert, [2401,3041) ffT, [3041,13793) silu, [13793,13953) pad
__global__ __launch_bounds__(256) void k_l0(
    const float* __restrict__ s0, const float* __restrict__ s1,
    const float* __restrict__ s2, const float* __restrict__ s3,
    const float* __restrict__ s4, const float* __restrict__ s5,
    const float* __restrict__ s6, const float* __restrict__ s7,
    const float* __restrict__ s8, const float* __restrict__ s9,
    const float* __restrict__ s10, u16* __restrict__ pool,
    const float* __restrict__ bk, const float* __restrict__ bv,
    float* __restrict__ bkv,
    const float* __restrict__ ff, u16* __restrict__ ffT,
    const float* __restrict__ in0, const float* __restrict__ w0,
    const float* __restrict__ b0, u16* __restrict__ o0,
    const float* __restrict__ in1, const float* __restrict__ w1,
    const float* __restrict__ b1, u16* __restrict__ o1,
    const float* __restrict__ in2, const float* __restrict__ w2,
    const float* __restrict__ b2, u16* __restrict__ o2,
    u16* __restrict__ Qaug, u16* __restrict__ Kaug, float* __restrict__ kk2) {
  __shared__ u16 sT[32][72];
  int blk = blockIdx.x, t = threadIdx.x;
  if (blk < 2401) {
    int i4 = blk * 256 + t;
    if (i4 < TOTW / 4) {
      int idx = i4 * 4;
      const float* src; int off;
      if      (idx < OFF_FAW)   { src = s0;  off = OFF_POSW2; }
      else if (idx < OFF_SAW)   { src = s1;  off = OFF_FAW; }
      else if (idx < OFF_WQ)    { src = s2;  off = OFF_SAW; }
      else if (idx < OFF_WKV)   { src = s3;  off = OFF_WQ; }
      else if (idx < 1343488)   { src = s4;  off = OFF_WKV; }
      else if (idx < OFF_PLKW2) { src = s5;  off = 1343488; }
      else if (idx < OFF_SXYW2) { src = s6;  off = OFF_PLKW2; }
      else if (idx < OFF_WQG)   { src = s7;  off = OFF_SXYW2; }
      else if (idx < OFF_WKG)   { src = s8;  off = OFF_WQG; }
      else if (idx < OFF_SATT)  { src = s9;  off = OFF_WKG; }
      else                      { src = s10; off = OFF_SATT; }
      float4 v = *(const float4*)(src + (idx - off));
      ushort4 o;
      o.x = f2bf(v.x); o.y = f2bf(v.y); o.z = f2bf(v.z); o.w = f2bf(v.w);
      *(ushort4*)(pool + idx) = o;
    } else if (i4 < TOTW / 4 + 256) {
      int j = (i4 - TOTW / 4) * 4;
#pragma unroll
      for (int e = 0; e < 4; ++e) {
        int b = j + e;
        bkv[b] = (b < 512) ? bk[b] : bv[b - 512];
      }
    }
  } else if (blk < 3041) {
    int lb = blk - 2401;
    int n0 = (lb & 63) * 64, c0 = (lb >> 6) * 32;
    {
      int cr = t >> 3, nc = (t & 7) * 8;
      const float* src = ff + (size_t)(c0 + cr) * NF + n0 + nc;
      float4 v0 = *(const float4*)src, v1 = *(const float4*)(src + 4);
      bf8v p;
      p[0]=(short)f2bf(v0.x); p[1]=(short)f2bf(v0.y); p[2]=(short)f2bf(v0.z); p[3]=(short)f2bf(v0.w);
      p[4]=(short)f2bf(v1.x); p[5]=(short)f2bf(v1.y); p[6]=(short)f2bf(v1.z); p[7]=(short)f2bf(v1.w);
      *(bf8v*)&sT[cr][nc] = p;
    }
    __syncthreads();
    {
      int r = t >> 2, cc = (t & 3) * 8;
      bf8v p;
#pragma unroll
      for (int e = 0; e < 8; ++e) p[e] = (short)sT[cc + e][r];
      *(bf8v*)(ffT + (size_t)(n0 + r) * 320 + c0 + cc) = p;
    }
  } else if (blk < 13793) {
    int lb = blk - 3041;
    const float *in, *w, *b; u16* o; int mlog, K, idx;
    if (lb < 8192)       { in = in0; w = w0; b = b0; o = o0; mlog = 9; K = 2; idx = lb * 256 + t; }
    else if (lb < 10240) { in = in1; w = w1; b = b1; o = o1; mlog = 7; K = 6; idx = (lb - 8192) * 256 + t; }
    else                 { in = in2; w = w2; b = b2; o = o2; mlog = 7; K = 2; idx = (lb - 10240) * 256 + t; }
    int M = 1 << mlog;
    int n = idx >> mlog, m = idx & (M - 1);
    float acc = b[m];
    for (int k = 0; k < K; ++k) acc += in[n * K + k] * w[m * K + k];
    o[idx] = f2bf(acc / (1.f + __expf(-acc)));
  } else {
    // aug cross dims [80:96) + kk2 (depends only on inputs)
    int id = (blk - 13793) * 256 + t;       // 40960 total
    int side = id >= NF * 8;
    int lid = side ? id - NF * 8 : id;
    int n = lid >> 3, h = lid & 7;
    const float* xy = side ? in2 : in0;     // sat_xy : bev_xy
    u16* aug = side ? Kaug : Qaug;
    int nrows = side ? NS : NF;
    float x = xy[n * 2], y = xy[n * 2 + 1];
    bf8v p0, z;
#pragma unroll
    for (int e = 0; e < 8; ++e) { p0[e] = 0; z[e] = 0; }
    p0[0] = (short)f2bf(S2L * x);
    p0[1] = (short)f2bf(S2L * y);
    u16* dst = aug + ((size_t)h * nrows + n) * DA + 80;
    *(bf8v*)dst = p0;
    *(bf8v*)(dst + 8) = z;
    if (side && h == 0) kk2[n] = L2E * (x * x + y * y) + SMAX;
  }
}

// ================= 128x64-tile GEMM body (plain epilogue only) — for L1 =================
__device__ __forceinline__ void gemm_body128(const u16* __restrict__ A, const u16* __restrict__ W,
                                             const float* __restrict__ bias, u16* __restrict__ out,
                                             int m0, int n0, int N, int K) {
  __shared__ u16 sA[2][128 * 64];
  __shared__ u16 sB[2][64 * 64];
  const int tid = threadIdx.x, w = tid >> 6, lane = tid & 63;
  const int l16 = lane & 15, lh = lane >> 4;

  f4v acc[2][4];
#pragma unroll
  for (int m = 0; m < 2; ++m)
#pragma unroll
    for (int j = 0; j < 4; ++j) acc[m][j] = (f4v){0.f, 0.f, 0.f, 0.f};

  auto stageA = [&](int buf, int k0) {
#pragma unroll
    for (int i = 0; i < 4; ++i) {
      int c = i * 256 + tid;
      int row = c >> 3, cp = c & 7;
      int sc_ = cp ^ (row & 7);
      gld16(A + (size_t)(m0 + row) * K + k0 + sc_ * 8, &sA[buf][c * 8]);
    }
  };
  auto stageB = [&](int buf, int k0) {
#pragma unroll
    for (int i = 0; i < 2; ++i) {
      int c = i * 256 + tid;
      int row = c >> 3, cp = c & 7;
      int sc_ = cp ^ (row & 7);
      gld16(W + (size_t)(n0 + row) * K + k0 + sc_ * 8, &sB[buf][c * 8]);
    }
  };

  stageA(0, 0); stageB(0, 0);
  __syncthreads();
  const int NK = K >> 6;
  for (int ks = 0; ks < NK; ++ks) {
    int nb = ks & 1;
    if (ks + 1 < NK) { stageA(nb ^ 1, (ks + 1) * 64); stageB(nb ^ 1, (ks + 1) * 64); }
#pragma unroll
    for (int kk = 0; kk < 2; ++kk) {
      bf8v af[2], bfr[4];
#pragma unroll
      for (int m = 0; m < 2; ++m) {
        int row = w * 32 + m * 16 + l16;
        int cp = (kk * 4 + lh) ^ (row & 7);
        af[m] = *(const bf8v*)&sA[nb][row * 64 + cp * 8];
      }
#pragma unroll
      for (int j = 0; j < 4; ++j) {
        int row = j * 16 + l16;
        int cp = (kk * 4 + lh) ^ (row & 7);
        bfr[j] = *(const bf8v*)&sB[nb][row * 64 + cp * 8];
      }
#pragma unroll
      for (int m = 0; m < 2; ++m)
#pragma unroll
        for (int j = 0; j < 4; ++j) acc[m][j] = mfma16(af[m], bfr[j], acc[m][j]);
    }
    __syncthreads();
  }
#pragma unroll
  for (int m = 0; m < 2; ++m) {
    int grow = m0 + w * 32 + m * 16 + (lh << 2);
#pragma unroll
    for (int j = 0; j < 4; ++j) {
      int gcol = n0 + j * 16 + l16;
      float bvs = bias ? bias[gcol] : 0.f;
#pragma unroll
      for (int r = 0; r < 4; ++r)
        out[(size_t)(grow + r) * N + gcol] = f2bf(acc[m][j][r] + bvs);
    }
  }
}

// ================= 64x64-tile GEMM body, fused epilogues — for L2 =================
__device__ __forceinline__ void gemm_body(const u16* __restrict__ A, const u16* __restrict__ W,
                                          const float* __restrict__ bias, u16* __restrict__ out,
                                          int m0, int n0, int N, int K,
                                          int mode, float scale, const float* __restrict__ xy,
                                          u16* __restrict__ aug, int nrows) {
  constexpr int MR = 2, NR = 2;        // per-wave 32x32
  __shared__ u16 sA[2][64 * 64];
  __shared__ u16 sB[2][64 * 64];
  const int tid = threadIdx.x, w = tid >> 6, lane = tid & 63;
  const int l16 = lane & 15, lh = lane >> 4;
  const int wr = w >> 1, wc = w & 1;

  f4v acc[MR][NR];
#pragma unroll
  for (int m = 0; m < MR; ++m)
#pragma unroll
    for (int j = 0; j < NR; ++j) acc[m][j] = (f4v){0.f, 0.f, 0.f, 0.f};

  auto stageA = [&](int buf, int k0) {
#pragma unroll
    for (int i = 0; i < 2; ++i) {
      int c = i * 256 + tid;
      int row = c >> 3, cp = c & 7;
      int sc_ = cp ^ (row & 7);
      gld16(A + (size_t)(m0 + row) * K + k0 + sc_ * 8, &sA[buf][c * 8]);
    }
  };
  auto stageB = [&](int buf, int k0) {
#pragma unroll
    for (int i = 0; i < 2; ++i) {
      int c = i * 256 + tid;
      int row = c >> 3, cp = c & 7;
      int sc_ = cp ^ (row & 7);
      gld16(W + (size_t)(n0 + row) * K + k0 + sc_ * 8, &sB[buf][c * 8]);
    }
  };

  stageA(0, 0); stageB(0, 0);
  __syncthreads();
  const int NK = K >> 6;
  for (int ks = 0; ks < NK; ++ks) {
    int nb = ks & 1;
    if (ks + 1 < NK) { stageA(nb ^ 1, (ks + 1) * 64); stageB(nb ^ 1, (ks + 1) * 64); }
#pragma unroll
    for (int kk = 0; kk < 2; ++kk) {
      bf8v af[MR], bfr[NR];
#pragma unroll
      for (int m = 0; m < MR; ++m) {
        int row = wr * 32 + m * 16 + l16;
        int cp = (kk * 4 + lh) ^ (row & 7);
        af[m] = *(const bf8v*)&sA[nb][row * 64 + cp * 8];
      }
#pragma unroll
      for (int j = 0; j < NR; ++j) {
        int row = wc * 32 + j * 16 + l16;
        int cp = (kk * 4 + lh) ^ (row & 7);
        bfr[j] = *(const bf8v*)&sB[nb][row * 64 + cp * 8];
      }
#pragma unroll
      for (int m = 0; m < MR; ++m)
#pragma unroll
        for (int j = 0; j < NR; ++j) acc[m][j] = mfma16(af[m], bfr[j], acc[m][j]);
    }
    __syncthreads();
  }

  if (mode == EPI_OUT) {
#pragma unroll
    for (int m = 0; m < MR; ++m) {
      int grow = m0 + wr * 32 + m * 16 + (lh << 2);
#pragma unroll
      for (int j = 0; j < NR; ++j) {
        int gcol = n0 + wc * 32 + j * 16 + l16;
        float bvs = bias ? bias[gcol] : 0.f;
#pragma unroll
        for (int r = 0; r < 4; ++r)
          out[(size_t)(grow + r) * N + gcol] = f2bf(acc[m][j][r] + bvs);
      }
    }
  } else if (mode == EPI_ROPE) {
    // main dims -> aug[0:64) with 2D rope on d<32 (wc==0 waves), scale folded
    float fr = __expf(-(float)(l16 & 7) * 1.1512925465f);   // 10000^(-(d&7)/8)
#pragma unroll
    for (int m = 0; m < MR; ++m) {
      int grow = m0 + wr * 32 + m * 16 + (lh << 2);
#pragma unroll
      for (int j = 0; j < NR; ++j) {
        int gcol = n0 + wc * 32 + j * 16 + l16;
        int h = gcol >> 6, d = gcol & 63;
        float bvs = bias[gcol];
#pragma unroll
        for (int r = 0; r < 4; ++r) {
          int n = grow + r;
          float val = acc[m][j][r] + bvs;
          float part = __shfl_xor(val, 8);
          float outv = val;
          if (wc == 0) {          // d < 32: rope (wave-uniform branch)
            float2 c2 = ((const float2*)xy)[n];
            float coord = j ? c2.y : c2.x;
            float sn, cs;
            __sincosf(coord * fr, &sn, &cs);
            outv = (l16 & 8) ? (part * sn + val * cs) : (val * cs - part * sn);
          }
          aug[((size_t)h * nrows + n) * DA + d] = f2bf(outv * scale);
        }
      }
    }
  } else if (mode == EPI_VT) {
    // V columns -> VT[h][d][n] (4 consecutive n per lane = ushort4)
#pragma unroll
    for (int m = 0; m < MR; ++m) {
      int grow = m0 + wr * 32 + m * 16 + (lh << 2);
#pragma unroll
      for (int j = 0; j < NR; ++j) {
        int gcol = n0 + wc * 32 + j * 16 + l16;
        int vcol = gcol - 512;
        int h = vcol >> 6, d = vcol & 63;
        float bvs = bias[gcol];
        ushort4 o;
        o.x = f2bf(acc[m][j][0] + bvs);
        o.y = f2bf(acc[m][j][1] + bvs);
        o.z = f2bf(acc[m][j][2] + bvs);
        o.w = f2bf(acc[m][j][3] + bvs);
        *(ushort4*)(aug + ((size_t)(h * 64 + d)) * NS + grow) = o;
      }
    }
  } else {
    // geo head -> aug[64:80), scale folded
#pragma unroll
    for (int m = 0; m < MR; ++m) {
      int grow = m0 + wr * 32 + m * 16 + (lh << 2);
#pragma unroll
      for (int j = 0; j < NR; ++j) {
        int gcol = n0 + wc * 32 + j * 16 + l16;
        int h = gcol >> 4, dg = gcol & 15;
        float bvs = bias[gcol];
#pragma unroll
        for (int r = 0; r < 4; ++r)
          aug[((size_t)h * nrows + grow + r) * DA + 64 + dg] = f2bf((acc[m][j][r] + bvs) * scale);
      }
    }
  }
}

struct GP { const u16* A; const u16* W; const float* bias; u16* out;
            int K; int N; int M; int mode; float scale; const float* xy;
            u16* aug; int nrows; };

__device__ __forceinline__ void gemm_dispatch128(const GP& g, int blk) {
  int mt = g.M >> 7;
  int m0 = (blk % mt) * 128, n0 = (blk / mt) * 64;
  gemm_body128(g.A, g.W, g.bias, g.out, m0, n0, g.N, g.K);
}
__device__ __forceinline__ void gemm_dispatch(const GP& g, int blk) {
  int mt = g.M >> 6;
  int m0 = (blk % mt) * 64, n0 = (blk / mt) * 64;
  gemm_body(g.A, g.W, g.bias, g.out, m0, n0, g.N, g.K,
            g.mode, g.scale, g.xy, g.aug, g.nrows);
}

// L1 (128x64 tiles): pos(256) feat(256) sat(64) geo1q(64) geo1k(16) = 656 blocks
__global__ __launch_bounds__(256) void k_gemm_L1(GP a, GP b, GP c, GP d, GP e) {
  int blk = blockIdx.x;
  if (blk < 256)       gemm_dispatch128(a, blk);
  else if (blk < 512)  gemm_dispatch128(b, blk - 256);
  else if (blk < 576)  gemm_dispatch128(c, blk - 512);
  else if (blk < 640)  gemm_dispatch128(d, blk - 576);
  else                 gemm_dispatch128(e, blk - 640);
}
// L2 (64x64 tiles): q(512) kv(256) geo2q(128) geo2k(32) = 928 blocks; fused prep epilogues
__global__ __launch_bounds__(256) void k_gemm_L2(GP a, GP b, GP c, GP d, u16* VTp) {
  int blk = blockIdx.x;
  if (blk < 512) {
    gemm_dispatch(a, blk);
  } else if (blk < 768) {
    int lb = blk - 512;
    int m0 = (lb & 15) * 64, n0 = (lb >> 4) * 64;
    if (n0 >= 512)
      gemm_body(b.A, b.W, b.bias, b.out, m0, n0, b.N, b.K, EPI_VT, 1.f, nullptr, VTp, NS);
    else
      gemm_body(b.A, b.W, b.bias, b.out, m0, n0, b.N, b.K, b.mode, b.scale, b.xy, b.aug, b.nrows);
  } else if (blk < 896) {
    gemm_dispatch(c, blk - 768);
  } else {
    gemm_dispatch(d, blk - 896);
  }
}

// ================= merged LayerNorms =================
// blocks: [0,1024) front chain, [1024,1280) sat D=512, [1280,2560) geo D=128
__global__ __launch_bounds__(256) void k_ln_all(
    const u16* __restrict__ feat_pre, const u16* __restrict__ pos,
    const float* __restrict__ fg, const float* __restrict__ fb,
    const float* __restrict__ qg, const float* __restrict__ qb2,
    u16* __restrict__ q_embed,
    const u16* __restrict__ satf_pre, const float* __restrict__ sg,
    const float* __restrict__ sb, u16* __restrict__ satf,
    const u16* __restrict__ ginq, const u16* __restrict__ gink,
    const float* __restrict__ ggq, const float* __restrict__ gbq,
    const float* __restrict__ ggk, const float* __restrict__ gbk,
    u16* __restrict__ goutq, u16* __restrict__ goutk) {
  int blk = blockIdx.x;
  int w = threadIdx.x >> 6, lane = threadIdx.x & 63;
  if (blk < 1024) {
    int row = blk * 4 + w;
    bf8v v = *(const bf8v*)(feat_pre + (size_t)row * 512 + lane * 8);
    float x[8];
#pragma unroll
    for (int e = 0; e < 8; ++e) x[e] = bf2f((u16)v[e]);
    float s = 0.f, q = 0.f;
#pragma unroll
    for (int e = 0; e < 8; ++e) { s += x[e]; q += x[e] * x[e]; }
#pragma unroll
    for (int mm = 1; mm < 64; mm <<= 1) { s += __shfl_xor(s, mm); q += __shfl_xor(q, mm); }
    float mean = s / 512.f, var = q / 512.f - mean * mean;
    float rstd = rsqrtf(var + 1e-5f);
    bf8v vp = *(const bf8v*)(pos + (size_t)row * 512 + lane * 8);
#pragma unroll
    for (int e = 0; e < 8; ++e)
      x[e] = (x[e] - mean) * rstd * fg[lane * 8 + e] + fb[lane * 8 + e] + bf2f((u16)vp[e]);
    s = 0.f; q = 0.f;
#pragma unroll
    for (int e = 0; e < 8; ++e) { s += x[e]; q += x[e] * x[e]; }
#pragma unroll
    for (int mm = 1; mm < 64; mm <<= 1) { s += __shfl_xor(s, mm); q += __shfl_xor(q, mm); }
    mean = s / 512.f; var = q / 512.f - mean * mean;
    rstd = rsqrtf(var + 1e-5f);
    bf8v ov;
#pragma unroll
    for (int e = 0; e < 8; ++e)
      ov[e] = (short)f2bf((x[e] - mean) * rstd * qg[lane * 8 + e] + qb2[lane * 8 + e]);
    *(bf8v*)(q_embed + (size_t)row * 512 + lane * 8) = ov;
  } else if (blk < 1280) {
    int row = (blk - 1024) * 4 + w;
    bf8v v = *(const bf8v*)(satf_pre + (size_t)row * 512 + lane * 8);
    float x[8];
#pragma unroll
    for (int e = 0; e < 8; ++e) x[e] = bf2f((u16)v[e]);
    float s = 0.f, q = 0.f;
#pragma unroll
    for (int e = 0; e < 8; ++e) { s += x[e]; q += x[e] * x[e]; }
#pragma unroll
    for (int mm = 1; mm < 64; mm <<= 1) { s += __shfl_xor(s, mm); q += __shfl_xor(q, mm); }
    float mean = s / 512.f, var = q / 512.f - mean * mean;
    float rstd = rsqrtf(var + 1e-5f);
    bf8v ov;
#pragma unroll
    for (int e = 0; e < 8; ++e)
      ov[e] = (short)f2bf((x[e] - mean) * rstd * sg[lane * 8 + e] + sb[lane * 8 + e]);
    *(bf8v*)(satf + (size_t)row * 512 + lane * 8) = ov;
  } else {
    int row = (blk - 1280) * 4 + w;
    const u16* in; const float *g, *b; u16* out;
    if (row < 4096) { in = ginq; g = ggq; b = gbq; out = goutq; }
    else { row -= 4096; in = gink; g = ggk; b = gbk; out = goutk; }
    uint32_t v = *(const uint32_t*)(in + (size_t)row * 128 + lane * 2);
    float x0 = bf2f((u16)(v & 0xffff)), x1 = bf2f((u16)(v >> 16));
    float s = x0 + x1, q = x0 * x0 + x1 * x1;
#pragma unroll
    for (int mm = 1; mm < 64; mm <<= 1) { s += __shfl_xor(s, mm); q += __shfl_xor(q, mm); }
    float mean = s / 128.f, var = q / 128.f - mean * mean;
    float rstd = rsqrtf(var + 1e-5f);
    u16 o0 = f2bf((x0 - mean) * rstd * g[lane * 2] + b[lane * 2]);
    u16 o1 = f2bf((x1 - mean) * rstd * g[lane * 2 + 1] + b[lane * 2 + 1]);
    *(uint32_t*)(out + (size_t)row * 128 + lane * 2) = (uint32_t)o0 | ((uint32_t)o1 << 16);
  }
}

// ================= fused flash attention v3: NO K/V staging (L2-resident), no barriers =================
// K/V working set = 324 KB/head, 2.6 MB total -> fits every XCD L2. Fragments read directly
// from global; only wave-private sP (P roundtrip) + sKK remain in LDS.
__global__ __launch_bounds__(256, 4) void k_flash(const u16* __restrict__ Qa,
                                                  const u16* __restrict__ Ka,
                                                  const u16* __restrict__ VT,
                                                  const float* __restrict__ kk2,
                                                  u16* __restrict__ Opart,
                                                  float* __restrict__ lbuf) {
  const int bid = blockIdx.x;
  const int h = bid & 7, qb = (bid >> 3) & 63, sp = bid >> 9;
  const int tid = threadIdx.x, w = tid >> 6, lane = tid & 63;
  const int l16 = lane & 15, lh = lane >> 4;
  __shared__ u16 sP[4][16][68];
  __shared__ float sKK[512];

  ((float2*)sKK)[tid] = ((const float2*)(kk2 + sp * 512))[tid];

  const int qrow = qb * 64 + w * 16 + l16;
  bf8v qf[3];
#pragma unroll
  for (int c = 0; c < 3; ++c)
    qf[c] = *(const bf8v*)(Qa + (size_t)(h * NF + qrow) * DA + c * 32 + lh * 8);

  bf8v ONES;
#pragma unroll
  for (int i = 0; i < 8; ++i) ONES[i] = (short)0x3F80;

  const int crow = qb * 64 + w * 16 + (lh << 2);
  float l_run[4] = {0.f, 0.f, 0.f, 0.f};
  f4v accO[4];
#pragma unroll
  for (int d = 0; d < 4; ++d) accO[d] = (f4v){0.f, 0.f, 0.f, 0.f};

  const int kt0 = sp * (NS / 64 / NSPLIT);
  const u16* Kbase = Ka + (size_t)h * NS * DA;
  const u16* Vbase = VT + (size_t)h * HD * NS;

  __syncthreads();    // sKK ready (only sync in the kernel)
  const int NT = NS / 64 / NSPLIT;   // 8 tiles per block
  for (int t8 = 0; t8 < NT; ++t8) {
    const int kb = (kt0 + t8) * 64;
    // ---- S = Qaug.Kaug, K fragments straight from L2 ----
#pragma unroll
    for (int j = 0; j < 4; ++j) {
      f4v s4 = (f4v){0.f, 0.f, 0.f, 0.f};
#pragma unroll
      for (int c = 0; c < 3; ++c) {
        bf8v kf = *(const bf8v*)(Kbase + (size_t)(kb + j * 16 + l16) * DA + c * 32 + lh * 8);
        s4 = mfma16(qf[c], kf, s4);
      }
      float ck = sKK[t8 * 64 + j * 16 + l16];
#pragma unroll
      for (int r = 0; r < 4; ++r) {
        float pv = exp2f(s4[r] - ck);
        sP[w][(lh << 2) + r][j * 16 + l16] = f2bf(pv);
      }
    }
    bf8v pf0 = *(const bf8v*)&sP[w][l16][lh * 8];
    bf8v pf1 = *(const bf8v*)&sP[w][l16][32 + lh * 8];
    f4v ls = (f4v){0.f, 0.f, 0.f, 0.f};
    ls = mfma16(pf0, ONES, ls);
    ls = mfma16(pf1, ONES, ls);
#pragma unroll
    for (int r = 0; r < 4; ++r) l_run[r] += ls[r];
    // ---- O += P.V, V fragments straight from L2 ----
#pragma unroll
    for (int c = 0; c < 2; ++c) {
      bf8v pf = (c == 0) ? pf0 : pf1;
#pragma unroll
      for (int d = 0; d < 4; ++d) {
        bf8v vf = *(const bf8v*)(Vbase + (size_t)(d * 16 + l16) * NS + kb + c * 32 + lh * 8);
        accO[d] = mfma16(pf, vf, accO[d]);
      }
    }
  }
  size_t obase = (size_t)(sp * 8 + h) * NF + crow;
#pragma unroll
  for (int d = 0; d < 4; ++d)
#pragma unroll
    for (int r = 0; r < 4; ++r)
      Opart[(obase + r) * 64 + d * 16 + l16] = f2bf(accO[d][r]);
  if (l16 == 0) {
#pragma unroll
    for (int r = 0; r < 4; ++r) lbuf[obase + r] = l_run[r];
  }
}

// ================= combine the NSPLIT splits (kernel boundary = cross-XCD sync) =================
__global__ void k_combine(const u16* __restrict__ Opart, const float* __restrict__ lbuf,
                          float* __restrict__ out) {
  int i4 = blockIdx.x * 256 + threadIdx.x;
  int n = i4 >> 7;
  int c4 = i4 & 127, h = c4 >> 4, d4 = c4 & 15;
  float l = 0.f, ox = 0.f, oy = 0.f, oz = 0.f, ow = 0.f;
#pragma unroll
  for (int s2 = 0; s2 < NSPLIT; ++s2) {
    size_t base = (size_t)(s2 * 8 + h) * NF + n;
    l += lbuf[base];
    ushort4 a = ((const ushort4*)(Opart + base * 64))[d4];
    ox += bf2f(a.x); oy += bf2f(a.y); oz += bf2f(a.z); ow += bf2f(a.w);
  }
  float rl = 1.f / l;
  ((float4*)out)[i4] = make_float4(ox * rl, oy * rl, oz * rl, ow * rl);
}

extern "C" void kernel_launch(void* const* d_in, const int* in_sizes, int n_in,
                              void* d_out, int out_size, void* d_ws, size_t ws_size,
                              hipStream_t stream) {
  (void)in_sizes; (void)n_in; (void)out_size; (void)ws_size;
  const float* front_feat = (const float*)d_in[0];
  const float* bev_xy     = (const float*)d_in[1];
  const float* sat_tokens = (const float*)d_in[2];
  const float* sat_xy     = (const float*)d_in[3];
  const float* plucker    = (const float*)d_in[4];
  const float* pos_w1 = (const float*)d_in[5];
  const float* pos_b1 = (const float*)d_in[6];
  const float* pos_w2 = (const float*)d_in[7];
  const float* pos_b2 = (const float*)d_in[8];
  const float* fa_w   = (const float*)d_in[9];
  const float* fa_b   = (const float*)d_in[10];
  const float* fa_ln_g = (const float*)d_in[11];
  const float* fa_ln_b = (const float*)d_in[12];
  const float* qn_g   = (const float*)d_in[13];
  const float* qn_b   = (const float*)d_in[14];
  const float* sa_w   = (const float*)d_in[15];
  const float* sa_b   = (const float*)d_in[16];
  const float* sa_ln_g = (const float*)d_in[17];
  const float* sa_ln_b = (const float*)d_in[18];
  const float* wq = (const float*)d_in[19];
  const float* bq = (const float*)d_in[20];
  const float* wk = (const float*)d_in[21];
  const float* bk = (const float*)d_in[22];
  const float* wv = (const float*)d_in[23];
  const float* bv = (const float*)d_in[24];
  const float* plk_w1 = (const float*)d_in[25];
  const float* plk_b1 = (const float*)d_in[26];
  const float* plk_w2 = (const float*)d_in[27];
  const float* plk_b2 = (const float*)d_in[28];
  const float* sxy_w1 = (const float*)d_in[29];
  const float* sxy_b1 = (const float*)d_in[30];
  const float* sxy_w2 = (const float*)d_in[31];
  const float* sxy_b2 = (const float*)d_in[32];
  const float* gqn_g = (const float*)d_in[33];
  const float* gqn_b = (const float*)d_in[34];
  const float* gkn_g = (const float*)d_in[35];
  const float* gkn_b = (const float*)d_in[36];
  const float* wqg = (const float*)d_in[37];
  const float* bqg = (const float*)d_in[38];
  const float* wkg = (const float*)d_in[39];
  const float* bkg = (const float*)d_in[40];

  char* ws = (char*)d_ws;
  size_t off = 0;
  auto alloc = [&](size_t bytes) {
    size_t r = off;
    off += (bytes + 255) & ~(size_t)255;
    return r;
  };
  u16*   wpool   = (u16*)(ws + alloc((size_t)TOTW * 2));
  float* bkv     = (float*)(ws + alloc(1024 * 4));
  u16*   ffT     = (u16*)(ws + alloc((size_t)NF * 320 * 2));
  u16*   pos_h   = (u16*)(ws + alloc((size_t)NF * MD * 2));
  u16*   plk_h   = (u16*)(ws + alloc((size_t)NF * GHID * 2));
  u16*   sxy_h   = (u16*)(ws + alloc((size_t)NS * GHID * 2));
  u16*   pos     = (u16*)(ws + alloc((size_t)NF * MD * 2));
  u16*   feat_pre= (u16*)(ws + alloc((size_t)NF * MD * 2));
  u16*   satf_pre= (u16*)(ws + alloc((size_t)NS * MD * 2));
  u16*   satf    = (u16*)(ws + alloc((size_t)NS * MD * 2));
  u16*   q_embed = (u16*)(ws + alloc((size_t)NF * MD * 2));
  u16*   plk2    = (u16*)(ws + alloc((size_t)NF * GHID * 2));
  u16*   sxy2    = (u16*)(ws + alloc((size_t)NS * GHID * 2));
  u16*   Qaug    = (u16*)(ws + alloc((size_t)8 * NF * DA * 2));
  u16*   Kaug    = (u16*)(ws + alloc((size_t)8 * NS * DA * 2));
  u16*   VT      = (u16*)(ws + alloc((size_t)8 * HD * NS * 2));
  float* kk2     = (float*)(ws + alloc((size_t)NS * 4));
  u16*   Opart   = (u16*)(ws + alloc((size_t)NSPLIT * 8 * NF * 64 * 2));
  float* lbuf    = (float*)(ws + alloc((size_t)NSPLIT * 8 * NF * 4));
  // aliases (producer dead before alias written)
  u16* plk_ln = plk_h;
  u16* sgf    = sxy_h;

  dim3 b256(256);
  // L0: convert + ffT + silus + aug pad/kk2
  k_l0<<<dim3(13953), b256, 0, stream>>>(
      pos_w2, fa_w, sa_w, wq, wk, wv, plk_w2, sxy_w2, wqg, wkg, sat_tokens,
      wpool, bk, bv, bkv, front_feat, ffT,
      bev_xy, pos_w1, pos_b1, pos_h,
      plucker, plk_w1, plk_b1, plk_h,
      sat_xy, sxy_w1, sxy_b1, sxy_h,
      Qaug, Kaug, kk2);

  // L1 GEMMs (128x64 tiles, plain epilogues)
  GP gpos {pos_h, wpool + OFF_POSW2, pos_b2, pos, 512, 512, 4096, EPI_OUT, 0.f, nullptr, nullptr, 0};
  GP gfeat{ffT, wpool + OFF_FAW, fa_b, feat_pre, 320, 512, 4096, EPI_OUT, 0.f, nullptr, nullptr, 0};
  GP gsat {wpool + OFF_SATT, wpool + OFF_SAW, sa_b, satf_pre, 768, 512, 1024, EPI_OUT, 0.f, nullptr, nullptr, 0};
  GP ggq1 {plk_h, wpool + OFF_PLKW2, plk_b2, plk2, 128, 128, 4096, EPI_OUT, 0.f, nullptr, nullptr, 0};
  GP ggk1 {sxy_h, wpool + OFF_SXYW2, sxy_b2, sxy2, 128, 128, 1024, EPI_OUT, 0.f, nullptr, nullptr, 0};
  k_gemm_L1<<<dim3(656), b256, 0, stream>>>(gpos, gfeat, gsat, ggq1, ggk1);

  // LNs
  k_ln_all<<<dim3(2560), b256, 0, stream>>>(
      feat_pre, pos, fa_ln_g, fa_ln_b, qn_g, qn_b, q_embed,
      satf_pre, sa_ln_g, sa_ln_b, satf,
      plk2, sxy2, gqn_g, gqn_b, gkn_g, gkn_b, plk_ln, sgf);

  // L2 GEMMs with fused rope/VT/geo epilogues (64x64 tiles)
  GP gq  {q_embed, wpool + OFF_WQ, bq, nullptr, 512, 512, 4096, EPI_ROPE, 0.125f * L2E, bev_xy, Qaug, NF};
  GP gkv {satf, wpool + OFF_WKV, bkv, nullptr, 512, 1024, 1024, EPI_ROPE, 1.f, sat_xy, Kaug, NS};
  GP ggq2{plk_ln, wpool + OFF_WQG, bqg, nullptr, 128, 128, 4096, EPI_GEO, 0.25f * L2E, nullptr, Qaug, NF};
  GP ggk2{sgf, wpool + OFF_WKG, bkg, nullptr, 128, 128, 1024, EPI_GEO, 1.f, nullptr, Kaug, NS};
  k_gemm_L2<<<dim3(928), b256, 0, stream>>>(gq, gkv, ggq2, ggk2, VT);

  // flash v3 (no staging, no barriers) + separate combine
  k_flash<<<dim3(1024), b256, 0, stream>>>(Qaug, Kaug, VT, kk2, Opart, lbuf);
  k_combine<<<dim3(NF * MD / 4 / 256), b256, 0, stream>>>(Opart, lbuf, (float*)d_out);
}

// Round 14
// 79.097 us; speedup vs baseline: 1.3546x; 1.3546x over previous
//
#include <hip/hip_runtime.h>
#include <hip/hip_bf16.h>
#include <stdint.h>

// Problem constants
#define NF 4096
#define NS 1024
#define MD 512
#define HD 64
#define DA 96
#define GHID 128

#define L2E 1.44269504f          // log2(e)
#define S2L 1.6986436f           // sqrt(2*log2e)  (LAMBDA_GEO=1)
#define SMAX 12.0f               // static softmax offset
#define NSPLIT 2                 // flash NS splits

typedef unsigned short u16;
typedef __attribute__((ext_vector_type(8))) short bf8v;   // 8 bf16
typedef __attribute__((ext_vector_type(4))) float f4v;

__device__ __forceinline__ u16 f2bf(float f) {
  __hip_bfloat16 h = __float2bfloat16(f);
  return __builtin_bit_cast(u16, h);
}
__device__ __forceinline__ float bf2f(u16 u) {
  union { unsigned u; float f; } v; v.u = ((unsigned)u) << 16; return v.f;
}
__device__ __forceinline__ f4v mfma16(bf8v a, bf8v b, f4v c) {
  return __builtin_amdgcn_mfma_f32_16x16x32_bf16(a, b, c, 0, 0, 0);
}
__device__ __forceinline__ void gld16(const void* g, void* l) {
  __builtin_amdgcn_global_load_lds(
      (const __attribute__((address_space(1))) unsigned int*)g,
      (__attribute__((address_space(3))) unsigned int*)l, 16, 0, 0);
}

// weight pool offsets (bf16 elements)
#define OFF_POSW2 0
#define OFF_FAW   262144
#define OFF_SAW   425984
#define OFF_WQ    819200
#define OFF_WKV   1081344
#define OFF_PLKW2 1605632
#define OFF_SXYW2 1622016
#define OFF_WQG   1638400
#define OFF_WKG   1654784
#define OFF_SATT  1671168
#define TOTW      2457600

// epilogue modes
#define EPI_OUT  0
#define EPI_ROPE 1
#define EPI_VT   2
#define EPI_GEO  3

// ================= L0: convert + ffT + silus + aug pad/cross dims + kk2 =================
// blocks: [0,2401) convert, [2401,3041) ffT, [3041,13793) silu, [13793,13953) pad
__global__ __launch_bounds__(256) void k_l0(
    const float* __restrict__ s0, const float* __restrict__ s1,
    const float* __restrict__ s2, const float* __restrict__ s3,
    const float* __restrict__ s4, const float* __restrict__ s5,
    const float* __restrict__ s6, const float* __restrict__ s7,
    const float* __restrict__ s8, const float* __restrict__ s9,
    const float* __restrict__ s10, u16* __restrict__ pool,
    const float* __restrict__ bk, const float* __restrict__ bv,
    float* __restrict__ bkv,
    const float* __restrict__ ff, u16* __restrict__ ffT,
    const float* __restrict__ in0, const float* __restrict__ w0,
    const float* __restrict__ b0, u16* __restrict__ o0,
    const float* __restrict__ in1, const float* __restrict__ w1,
    const float* __restrict__ b1, u16* __restrict__ o1,
    const float* __restrict__ in2, const float* __restrict__ w2,
    const float* __restrict__ b2, u16* __restrict__ o2,
    u16* __restrict__ Qaug, u16* __restrict__ Kaug, float* __restrict__ kk2) {
  __shared__ u16 sT[32][72];
  int blk = blockIdx.x, t = threadIdx.x;
  if (blk < 2401) {
    int i4 = blk * 256 + t;
    if (i4 < TOTW / 4) {
      int idx = i4 * 4;
      const float* src; int off;
      if      (idx < OFF_FAW)   { src = s0;  off = OFF_POSW2; }
      else if (idx < OFF_SAW)   { src = s1;  off = OFF_FAW; }
      else if (idx < OFF_WQ)    { src = s2;  off = OFF_SAW; }
      else if (idx < OFF_WKV)   { src = s3;  off = OFF_WQ; }
      else if (idx < 1343488)   { src = s4;  off = OFF_WKV; }
      else if (idx < OFF_PLKW2) { src = s5;  off = 1343488; }
      else if (idx < OFF_SXYW2) { src = s6;  off = OFF_PLKW2; }
      else if (idx < OFF_WQG)   { src = s7;  off = OFF_SXYW2; }
      else if (idx < OFF_WKG)   { src = s8;  off = OFF_WQG; }
      else if (idx < OFF_SATT)  { src = s9;  off = OFF_WKG; }
      else                      { src = s10; off = OFF_SATT; }
      float4 v = *(const float4*)(src + (idx - off));
      ushort4 o;
      o.x = f2bf(v.x); o.y = f2bf(v.y); o.z = f2bf(v.z); o.w = f2bf(v.w);
      *(ushort4*)(pool + idx) = o;
    } else if (i4 < TOTW / 4 + 256) {
      int j = (i4 - TOTW / 4) * 4;
#pragma unroll
      for (int e = 0; e < 4; ++e) {
        int b = j + e;
        bkv[b] = (b < 512) ? bk[b] : bv[b - 512];
      }
    }
  } else if (blk < 3041) {
    int lb = blk - 2401;
    int n0 = (lb & 63) * 64, c0 = (lb >> 6) * 32;
    {
      int cr = t >> 3, nc = (t & 7) * 8;
      const float* src = ff + (size_t)(c0 + cr) * NF + n0 + nc;
      float4 v0 = *(const float4*)src, v1 = *(const float4*)(src + 4);
      bf8v p;
      p[0]=(short)f2bf(v0.x); p[1]=(short)f2bf(v0.y); p[2]=(short)f2bf(v0.z); p[3]=(short)f2bf(v0.w);
      p[4]=(short)f2bf(v1.x); p[5]=(short)f2bf(v1.y); p[6]=(short)f2bf(v1.z); p[7]=(short)f2bf(v1.w);
      *(bf8v*)&sT[cr][nc] = p;
    }
    __syncthreads();
    {
      int r = t >> 2, cc = (t & 3) * 8;
      bf8v p;
#pragma unroll
      for (int e = 0; e < 8; ++e) p[e] = (short)sT[cc + e][r];
      *(bf8v*)(ffT + (size_t)(n0 + r) * 320 + c0 + cc) = p;
    }
  } else if (blk < 13793) {
    int lb = blk - 3041;
    const float *in, *w, *b; u16* o; int mlog, K, idx;
    if (lb < 8192)       { in = in0; w = w0; b = b0; o = o0; mlog = 9; K = 2; idx = lb * 256 + t; }
    else if (lb < 10240) { in = in1; w = w1; b = b1; o = o1; mlog = 7; K = 6; idx = (lb - 8192) * 256 + t; }
    else                 { in = in2; w = w2; b = b2; o = o2; mlog = 7; K = 2; idx = (lb - 10240) * 256 + t; }
    int M = 1 << mlog;
    int n = idx >> mlog, m = idx & (M - 1);
    float acc = b[m];
    for (int k = 0; k < K; ++k) acc += in[n * K + k] * w[m * K + k];
    o[idx] = f2bf(acc / (1.f + __expf(-acc)));
  } else {
    // aug cross dims [80:96) + kk2 (depends only on inputs)
    int id = (blk - 13793) * 256 + t;       // 40960 total
    int side = id >= NF * 8;
    int lid = side ? id - NF * 8 : id;
    int n = lid >> 3, h = lid & 7;
    const float* xy = side ? in2 : in0;     // sat_xy : bev_xy
    u16* aug = side ? Kaug : Qaug;
    int nrows = side ? NS : NF;
    float x = xy[n * 2], y = xy[n * 2 + 1];
    bf8v p0, z;
#pragma unroll
    for (int e = 0; e < 8; ++e) { p0[e] = 0; z[e] = 0; }
    p0[0] = (short)f2bf(S2L * x);
    p0[1] = (short)f2bf(S2L * y);
    u16* dst = aug + ((size_t)h * nrows + n) * DA + 80;
    *(bf8v*)dst = p0;
    *(bf8v*)(dst + 8) = z;
    if (side && h == 0) kk2[n] = L2E * (x * x + y * y) + SMAX;
  }
}

// ================= 128x64-tile GEMM body (plain epilogue only) — for L1 =================
__device__ __forceinline__ void gemm_body128(const u16* __restrict__ A, const u16* __restrict__ W,
                                             const float* __restrict__ bias, u16* __restrict__ out,
                                             int m0, int n0, int N, int K) {
  __shared__ u16 sA[2][128 * 64];
  __shared__ u16 sB[2][64 * 64];
  const int tid = threadIdx.x, w = tid >> 6, lane = tid & 63;
  const int l16 = lane & 15, lh = lane >> 4;

  f4v acc[2][4];
#pragma unroll
  for (int m = 0; m < 2; ++m)
#pragma unroll
    for (int j = 0; j < 4; ++j) acc[m][j] = (f4v){0.f, 0.f, 0.f, 0.f};

  auto stageA = [&](int buf, int k0) {
#pragma unroll
    for (int i = 0; i < 4; ++i) {
      int c = i * 256 + tid;
      int row = c >> 3, cp = c & 7;
      int sc_ = cp ^ (row & 7);
      gld16(A + (size_t)(m0 + row) * K + k0 + sc_ * 8, &sA[buf][c * 8]);
    }
  };
  auto stageB = [&](int buf, int k0) {
#pragma unroll
    for (int i = 0; i < 2; ++i) {
      int c = i * 256 + tid;
      int row = c >> 3, cp = c & 7;
      int sc_ = cp ^ (row & 7);
      gld16(W + (size_t)(n0 + row) * K + k0 + sc_ * 8, &sB[buf][c * 8]);
    }
  };

  stageA(0, 0); stageB(0, 0);
  __syncthreads();
  const int NK = K >> 6;
  for (int ks = 0; ks < NK; ++ks) {
    int nb = ks & 1;
    if (ks + 1 < NK) { stageA(nb ^ 1, (ks + 1) * 64); stageB(nb ^ 1, (ks + 1) * 64); }
#pragma unroll
    for (int kk = 0; kk < 2; ++kk) {
      bf8v af[2], bfr[4];
#pragma unroll
      for (int m = 0; m < 2; ++m) {
        int row = w * 32 + m * 16 + l16;
        int cp = (kk * 4 + lh) ^ (row & 7);
        af[m] = *(const bf8v*)&sA[nb][row * 64 + cp * 8];
      }
#pragma unroll
      for (int j = 0; j < 4; ++j) {
        int row = j * 16 + l16;
        int cp = (kk * 4 + lh) ^ (row & 7);
        bfr[j] = *(const bf8v*)&sB[nb][row * 64 + cp * 8];
      }
#pragma unroll
      for (int m = 0; m < 2; ++m)
#pragma unroll
        for (int j = 0; j < 4; ++j) acc[m][j] = mfma16(af[m], bfr[j], acc[m][j]);
    }
    __syncthreads();
  }
#pragma unroll
  for (int m = 0; m < 2; ++m) {
    int grow = m0 + w * 32 + m * 16 + (lh << 2);
#pragma unroll
    for (int j = 0; j < 4; ++j) {
      int gcol = n0 + j * 16 + l16;
      float bvs = bias ? bias[gcol] : 0.f;
#pragma unroll
      for (int r = 0; r < 4; ++r)
        out[(size_t)(grow + r) * N + gcol] = f2bf(acc[m][j][r] + bvs);
    }
  }
}

// ================= 64x64-tile GEMM body, fused epilogues — for L2 =================
__device__ __forceinline__ void gemm_body(const u16* __restrict__ A, const u16* __restrict__ W,
                                          const float* __restrict__ bias, u16* __restrict__ out,
                                          int m0, int n0, int N, int K,
                                          int mode, float scale, const float* __restrict__ xy,
                                          u16* __restrict__ aug, int nrows) {
  constexpr int MR = 2, NR = 2;        // per-wave 32x32
  __shared__ u16 sA[2][64 * 64];
  __shared__ u16 sB[2][64 * 64];
  const int tid = threadIdx.x, w = tid >> 6, lane = tid & 63;
  const int l16 = lane & 15, lh = lane >> 4;
  const int wr = w >> 1, wc = w & 1;

  f4v acc[MR][NR];
#pragma unroll
  for (int m = 0; m < MR; ++m)
#pragma unroll
    for (int j = 0; j < NR; ++j) acc[m][j] = (f4v){0.f, 0.f, 0.f, 0.f};

  auto stageA = [&](int buf, int k0) {
#pragma unroll
    for (int i = 0; i < 2; ++i) {
      int c = i * 256 + tid;
      int row = c >> 3, cp = c & 7;
      int sc_ = cp ^ (row & 7);
      gld16(A + (size_t)(m0 + row) * K + k0 + sc_ * 8, &sA[buf][c * 8]);
    }
  };
  auto stageB = [&](int buf, int k0) {
#pragma unroll
    for (int i = 0; i < 2; ++i) {
      int c = i * 256 + tid;
      int row = c >> 3, cp = c & 7;
      int sc_ = cp ^ (row & 7);
      gld16(W + (size_t)(n0 + row) * K + k0 + sc_ * 8, &sB[buf][c * 8]);
    }
  };

  stageA(0, 0); stageB(0, 0);
  __syncthreads();
  const int NK = K >> 6;
  for (int ks = 0; ks < NK; ++ks) {
    int nb = ks & 1;
    if (ks + 1 < NK) { stageA(nb ^ 1, (ks + 1) * 64); stageB(nb ^ 1, (ks + 1) * 64); }
#pragma unroll
    for (int kk = 0; kk < 2; ++kk) {
      bf8v af[MR], bfr[NR];
#pragma unroll
      for (int m = 0; m < MR; ++m) {
        int row = wr * 32 + m * 16 + l16;
        int cp = (kk * 4 + lh) ^ (row & 7);
        af[m] = *(const bf8v*)&sA[nb][row * 64 + cp * 8];
      }
#pragma unroll
      for (int j = 0; j < NR; ++j) {
        int row = wc * 32 + j * 16 + l16;
        int cp = (kk * 4 + lh) ^ (row & 7);
        bfr[j] = *(const bf8v*)&sB[nb][row * 64 + cp * 8];
      }
#pragma unroll
      for (int m = 0; m < MR; ++m)
#pragma unroll
        for (int j = 0; j < NR; ++j) acc[m][j] = mfma16(af[m], bfr[j], acc[m][j]);
    }
    __syncthreads();
  }

  if (mode == EPI_OUT) {
#pragma unroll
    for (int m = 0; m < MR; ++m) {
      int grow = m0 + wr * 32 + m * 16 + (lh << 2);
#pragma unroll
      for (int j = 0; j < NR; ++j) {
        int gcol = n0 + wc * 32 + j * 16 + l16;
        float bvs = bias ? bias[gcol] : 0.f;
#pragma unroll
        for (int r = 0; r < 4; ++r)
          out[(size_t)(grow + r) * N + gcol] = f2bf(acc[m][j][r] + bvs);
      }
    }
  } else if (mode == EPI_ROPE) {
    // main dims -> aug[0:64) with 2D rope on d<32 (wc==0 waves), scale folded
    float fr = __expf(-(float)(l16 & 7) * 1.1512925465f);   // 10000^(-(d&7)/8)
#pragma unroll
    for (int m = 0; m < MR; ++m) {
      int grow = m0 + wr * 32 + m * 16 + (lh << 2);
#pragma unroll
      for (int j = 0; j < NR; ++j) {
        int gcol = n0 + wc * 32 + j * 16 + l16;
        int h = gcol >> 6, d = gcol & 63;
        float bvs = bias[gcol];
#pragma unroll
        for (int r = 0; r < 4; ++r) {
          int n = grow + r;
          float val = acc[m][j][r] + bvs;
          float part = __shfl_xor(val, 8);
          float outv = val;
          if (wc == 0) {          // d < 32: rope (wave-uniform branch)
            float2 c2 = ((const float2*)xy)[n];
            float coord = j ? c2.y : c2.x;
            float sn, cs;
            __sincosf(coord * fr, &sn, &cs);
            outv = (l16 & 8) ? (part * sn + val * cs) : (val * cs - part * sn);
          }
          aug[((size_t)h * nrows + n) * DA + d] = f2bf(outv * scale);
        }
      }
    }
  } else if (mode == EPI_VT) {
    // V columns -> VT[h][d][n] (4 consecutive n per lane = ushort4)
#pragma unroll
    for (int m = 0; m < MR; ++m) {
      int grow = m0 + wr * 32 + m * 16 + (lh << 2);
#pragma unroll
      for (int j = 0; j < NR; ++j) {
        int gcol = n0 + wc * 32 + j * 16 + l16;
        int vcol = gcol - 512;
        int h = vcol >> 6, d = vcol & 63;
        float bvs = bias[gcol];
        ushort4 o;
        o.x = f2bf(acc[m][j][0] + bvs);
        o.y = f2bf(acc[m][j][1] + bvs);
        o.z = f2bf(acc[m][j][2] + bvs);
        o.w = f2bf(acc[m][j][3] + bvs);
        *(ushort4*)(aug + ((size_t)(h * 64 + d)) * NS + grow) = o;
      }
    }
  } else {
    // geo head -> aug[64:80), scale folded
#pragma unroll
    for (int m = 0; m < MR; ++m) {
      int grow = m0 + wr * 32 + m * 16 + (lh << 2);
#pragma unroll
      for (int j = 0; j < NR; ++j) {
        int gcol = n0 + wc * 32 + j * 16 + l16;
        int h = gcol >> 4, dg = gcol & 15;
        float bvs = bias[gcol];
#pragma unroll
        for (int r = 0; r < 4; ++r)
          aug[((size_t)h * nrows + grow + r) * DA + 64 + dg] = f2bf((acc[m][j][r] + bvs) * scale);
      }
    }
  }
}

struct GP { const u16* A; const u16* W; const float* bias; u16* out;
            int K; int N; int M; int mode; float scale; const float* xy;
            u16* aug; int nrows; };

__device__ __forceinline__ void gemm_dispatch128(const GP& g, int blk) {
  int mt = g.M >> 7;
  int m0 = (blk % mt) * 128, n0 = (blk / mt) * 64;
  gemm_body128(g.A, g.W, g.bias, g.out, m0, n0, g.N, g.K);
}
__device__ __forceinline__ void gemm_dispatch(const GP& g, int blk) {
  int mt = g.M >> 6;
  int m0 = (blk % mt) * 64, n0 = (blk / mt) * 64;
  gemm_body(g.A, g.W, g.bias, g.out, m0, n0, g.N, g.K,
            g.mode, g.scale, g.xy, g.aug, g.nrows);
}

// L1 (128x64 tiles): pos(256) feat(256) sat(64) geo1q(64) geo1k(16) = 656 blocks
__global__ __launch_bounds__(256) void k_gemm_L1(GP a, GP b, GP c, GP d, GP e) {
  int blk = blockIdx.x;
  if (blk < 256)       gemm_dispatch128(a, blk);
  else if (blk < 512)  gemm_dispatch128(b, blk - 256);
  else if (blk < 576)  gemm_dispatch128(c, blk - 512);
  else if (blk < 640)  gemm_dispatch128(d, blk - 576);
  else                 gemm_dispatch128(e, blk - 640);
}
// L2 (64x64 tiles): q(512) kv(256) geo2q(128) geo2k(32) = 928 blocks; fused prep epilogues
__global__ __launch_bounds__(256) void k_gemm_L2(GP a, GP b, GP c, GP d, u16* VTp) {
  int blk = blockIdx.x;
  if (blk < 512) {
    gemm_dispatch(a, blk);
  } else if (blk < 768) {
    int lb = blk - 512;
    int m0 = (lb & 15) * 64, n0 = (lb >> 4) * 64;
    if (n0 >= 512)
      gemm_body(b.A, b.W, b.bias, b.out, m0, n0, b.N, b.K, EPI_VT, 1.f, nullptr, VTp, NS);
    else
      gemm_body(b.A, b.W, b.bias, b.out, m0, n0, b.N, b.K, b.mode, b.scale, b.xy, b.aug, b.nrows);
  } else if (blk < 896) {
    gemm_dispatch(c, blk - 768);
  } else {
    gemm_dispatch(d, blk - 896);
  }
}

// ================= merged LayerNorms =================
// blocks: [0,1024) front chain, [1024,1280) sat D=512, [1280,2560) geo D=128
__global__ __launch_bounds__(256) void k_ln_all(
    const u16* __restrict__ feat_pre, const u16* __restrict__ pos,
    const float* __restrict__ fg, const float* __restrict__ fb,
    const float* __restrict__ qg, const float* __restrict__ qb2,
    u16* __restrict__ q_embed,
    const u16* __restrict__ satf_pre, const float* __restrict__ sg,
    const float* __restrict__ sb, u16* __restrict__ satf,
    const u16* __restrict__ ginq, const u16* __restrict__ gink,
    const float* __restrict__ ggq, const float* __restrict__ gbq,
    const float* __restrict__ ggk, const float* __restrict__ gbk,
    u16* __restrict__ goutq, u16* __restrict__ goutk) {
  int blk = blockIdx.x;
  int w = threadIdx.x >> 6, lane = threadIdx.x & 63;
  if (blk < 1024) {
    int row = blk * 4 + w;
    bf8v v = *(const bf8v*)(feat_pre + (size_t)row * 512 + lane * 8);
    float x[8];
#pragma unroll
    for (int e = 0; e < 8; ++e) x[e] = bf2f((u16)v[e]);
    float s = 0.f, q = 0.f;
#pragma unroll
    for (int e = 0; e < 8; ++e) { s += x[e]; q += x[e] * x[e]; }
#pragma unroll
    for (int mm = 1; mm < 64; mm <<= 1) { s += __shfl_xor(s, mm); q += __shfl_xor(q, mm); }
    float mean = s / 512.f, var = q / 512.f - mean * mean;
    float rstd = rsqrtf(var + 1e-5f);
    bf8v vp = *(const bf8v*)(pos + (size_t)row * 512 + lane * 8);
#pragma unroll
    for (int e = 0; e < 8; ++e)
      x[e] = (x[e] - mean) * rstd * fg[lane * 8 + e] + fb[lane * 8 + e] + bf2f((u16)vp[e]);
    s = 0.f; q = 0.f;
#pragma unroll
    for (int e = 0; e < 8; ++e) { s += x[e]; q += x[e] * x[e]; }
#pragma unroll
    for (int mm = 1; mm < 64; mm <<= 1) { s += __shfl_xor(s, mm); q += __shfl_xor(q, mm); }
    mean = s / 512.f; var = q / 512.f - mean * mean;
    rstd = rsqrtf(var + 1e-5f);
    bf8v ov;
#pragma unroll
    for (int e = 0; e < 8; ++e)
      ov[e] = (short)f2bf((x[e] - mean) * rstd * qg[lane * 8 + e] + qb2[lane * 8 + e]);
    *(bf8v*)(q_embed + (size_t)row * 512 + lane * 8) = ov;
  } else if (blk < 1280) {
    int row = (blk - 1024) * 4 + w;
    bf8v v = *(const bf8v*)(satf_pre + (size_t)row * 512 + lane * 8);
    float x[8];
#pragma unroll
    for (int e = 0; e < 8; ++e) x[e] = bf2f((u16)v[e]);
    float s = 0.f, q = 0.f;
#pragma unroll
    for (int e = 0; e < 8; ++e) { s += x[e]; q += x[e] * x[e]; }
#pragma unroll
    for (int mm = 1; mm < 64; mm <<= 1) { s += __shfl_xor(s, mm); q += __shfl_xor(q, mm); }
    float mean = s / 512.f, var = q / 512.f - mean * mean;
    float rstd = rsqrtf(var + 1e-5f);
    bf8v ov;
#pragma unroll
    for (int e = 0; e < 8; ++e)
      ov[e] = (short)f2bf((x[e] - mean) * rstd * sg[lane * 8 + e] + sb[lane * 8 + e]);
    *(bf8v*)(satf + (size_t)row * 512 + lane * 8) = ov;
  } else {
    int row = (blk - 1280) * 4 + w;
    const u16* in; const float *g, *b; u16* out;
    if (row < 4096) { in = ginq; g = ggq; b = gbq; out = goutq; }
    else { row -= 4096; in = gink; g = ggk; b = gbk; out = goutk; }
    uint32_t v = *(const uint32_t*)(in + (size_t)row * 128 + lane * 2);
    float x0 = bf2f((u16)(v & 0xffff)), x1 = bf2f((u16)(v >> 16));
    float s = x0 + x1, q = x0 * x0 + x1 * x1;
#pragma unroll
    for (int mm = 1; mm < 64; mm <<= 1) { s += __shfl_xor(s, mm); q += __shfl_xor(q, mm); }
    float mean = s / 128.f, var = q / 128.f - mean * mean;
    float rstd = rsqrtf(var + 1e-5f);
    u16 o0 = f2bf((x0 - mean) * rstd * g[lane * 2] + b[lane * 2]);
    u16 o1 = f2bf((x1 - mean) * rstd * g[lane * 2 + 1] + b[lane * 2 + 1]);
    *(uint32_t*)(out + (size_t)row * 128 + lane * 2) = (uint32_t)o0 | ((uint32_t)o1 << 16);
  }
}

// ================= fused flash attention (r9 version: staged K/V, static-offset softmax) =================
__global__ __launch_bounds__(256, 4) void k_flash(const u16* __restrict__ Qa,
                                                  const u16* __restrict__ Ka,
                                                  const u16* __restrict__ VT,
                                                  const float* __restrict__ kk2,
                                                  u16* __restrict__ Opart,
                                                  float* __restrict__ lbuf) {
  const int h = blockIdx.y, qb = blockIdx.x, sp = blockIdx.z;
  const int tid = threadIdx.x, w = tid >> 6, lane = tid & 63;
  const int l16 = lane & 15, lh = lane >> 4;
  __shared__ u16 sK[64][100];
  __shared__ u16 sV[64][68];
  __shared__ u16 sP[4][16][68];
  __shared__ float sKK[512];

  ((float2*)sKK)[tid] = ((const float2*)(kk2 + sp * 512))[tid];

  const int qrow = qb * 64 + w * 16 + l16;
  bf8v qf[3];
#pragma unroll
  for (int c = 0; c < 3; ++c)
    qf[c] = *(const bf8v*)(Qa + (size_t)(h * NF + qrow) * DA + c * 32 + lh * 8);

  bf8v ONES;
#pragma unroll
  for (int i = 0; i < 8; ++i) ONES[i] = (short)0x3F80;

  const int crow = qb * 64 + w * 16 + (lh << 2);
  float l_run[4] = {0.f, 0.f, 0.f, 0.f};
  f4v accO[4];
#pragma unroll
  for (int d = 0; d < 4; ++d) accO[d] = (f4v){0.f, 0.f, 0.f, 0.f};

  const int kt0 = sp * (NS / 64 / NSPLIT);
  bf8v kreg[3], vreg[2];
  auto sload = [&](int t8) {
    int kb = (kt0 + t8) * 64;
#pragma unroll
    for (int i = 0; i < 3; ++i) {
      int c = tid + i * 256; int r = c / 12, off = (c % 12) * 8;
      kreg[i] = *(const bf8v*)(Ka + ((size_t)(h * NS) + kb + r) * DA + off);
    }
#pragma unroll
    for (int i = 0; i < 2; ++i) {
      int c = tid + i * 256; int d = c >> 3, off = (c & 7) * 8;
      vreg[i] = *(const bf8v*)(VT + ((size_t)(h * HD) + d) * NS + kb + off);
    }
  };
  auto swrite = [&]() {
#pragma unroll
    for (int i = 0; i < 3; ++i) {
      int c = tid + i * 256; int r = c / 12, off = (c % 12) * 8;
      *(bf8v*)&sK[r][off] = kreg[i];
    }
#pragma unroll
    for (int i = 0; i < 2; ++i) {
      int c = tid + i * 256; int d = c >> 3, off = (c & 7) * 8;
      *(bf8v*)&sV[d][off] = vreg[i];
    }
  };

  sload(0); swrite();
  __syncthreads();
  const int NT = NS / 64 / NSPLIT;   // 8 tiles per block
  for (int t8 = 0; t8 < NT; ++t8) {
    if (t8 < NT - 1) sload(t8 + 1);
#pragma unroll
    for (int j = 0; j < 4; ++j) {
      f4v s4 = (f4v){0.f, 0.f, 0.f, 0.f};
#pragma unroll
      for (int c = 0; c < 3; ++c) {
        bf8v kf = *(const bf8v*)&sK[j * 16 + l16][c * 32 + lh * 8];
        s4 = mfma16(qf[c], kf, s4);
      }
      float ck = sKK[t8 * 64 + j * 16 + l16];
#pragma unroll
      for (int r = 0; r < 4; ++r) {
        float pv = exp2f(s4[r] - ck);
        sP[w][(lh << 2) + r][j * 16 + l16] = f2bf(pv);
      }
    }
    bf8v pf0 = *(const bf8v*)&sP[w][l16][lh * 8];
    bf8v pf1 = *(const bf8v*)&sP[w][l16][32 + lh * 8];
    f4v ls = (f4v){0.f, 0.f, 0.f, 0.f};
    ls = mfma16(pf0, ONES, ls);
    ls = mfma16(pf1, ONES, ls);
#pragma unroll
    for (int r = 0; r < 4; ++r) l_run[r] += ls[r];
#pragma unroll
    for (int c = 0; c < 2; ++c) {
      bf8v pf = (c == 0) ? pf0 : pf1;
#pragma unroll
      for (int d = 0; d < 4; ++d) {
        bf8v vf = *(const bf8v*)&sV[d * 16 + l16][c * 32 + lh * 8];
        accO[d] = mfma16(pf, vf, accO[d]);
      }
    }
    __syncthreads();
    if (t8 < NT - 1) swrite();
    __syncthreads();
  }
  size_t obase = (size_t)(sp * 8 + h) * NF + crow;
#pragma unroll
  for (int d = 0; d < 4; ++d)
#pragma unroll
    for (int r = 0; r < 4; ++r)
      Opart[(obase + r) * 64 + d * 16 + l16] = f2bf(accO[d][r]);
  if (l16 == 0) {
#pragma unroll
    for (int r = 0; r < 4; ++r) lbuf[obase + r] = l_run[r];
  }
}

// ================= combine the NSPLIT splits (kernel boundary = cross-XCD sync) =================
__global__ void k_combine(const u16* __restrict__ Opart, const float* __restrict__ lbuf,
                          float* __restrict__ out) {
  int i4 = blockIdx.x * 256 + threadIdx.x;
  int n = i4 >> 7;
  int c4 = i4 & 127, h = c4 >> 4, d4 = c4 & 15;
  float l = 0.f, ox = 0.f, oy = 0.f, oz = 0.f, ow = 0.f;
#pragma unroll
  for (int s2 = 0; s2 < NSPLIT; ++s2) {
    size_t base = (size_t)(s2 * 8 + h) * NF + n;
    l += lbuf[base];
    ushort4 a = ((const ushort4*)(Opart + base * 64))[d4];
    ox += bf2f(a.x); oy += bf2f(a.y); oz += bf2f(a.z); ow += bf2f(a.w);
  }
  float rl = 1.f / l;
  ((float4*)out)[i4] = make_float4(ox * rl, oy * rl, oz * rl, ow * rl);
}

extern "C" void kernel_launch(void* const* d_in, const int* in_sizes, int n_in,
                              void* d_out, int out_size, void* d_ws, size_t ws_size,
                              hipStream_t stream) {
  (void)in_sizes; (void)n_in; (void)out_size; (void)ws_size;
  const float* front_feat = (const float*)d_in[0];
  const float* bev_xy     = (const float*)d_in[1];
  const float* sat_tokens = (const float*)d_in[2];
  const float* sat_xy     = (const float*)d_in[3];
  const float* plucker    = (const float*)d_in[4];
  const float* pos_w1 = (const float*)d_in[5];
  const float* pos_b1 = (const float*)d_in[6];
  const float* pos_w2 = (const float*)d_in[7];
  const float* pos_b2 = (const float*)d_in[8];
  const float* fa_w   = (const float*)d_in[9];
  const float* fa_b   = (const float*)d_in[10];
  const float* fa_ln_g = (const float*)d_in[11];
  const float* fa_ln_b = (const float*)d_in[12];
  const float* qn_g   = (const float*)d_in[13];
  const float* qn_b   = (const float*)d_in[14];
  const float* sa_w   = (const float*)d_in[15];
  const float* sa_b   = (const float*)d_in[16];
  const float* sa_ln_g = (const float*)d_in[17];
  const float* sa_ln_b = (const float*)d_in[18];
  const float* wq = (const float*)d_in[19];
  const float* bq = (const float*)d_in[20];
  const float* wk = (const float*)d_in[21];
  const float* bk = (const float*)d_in[22];
  const float* wv = (const float*)d_in[23];
  const float* bv = (const float*)d_in[24];
  const float* plk_w1 = (const float*)d_in[25];
  const float* plk_b1 = (const float*)d_in[26];
  const float* plk_w2 = (const float*)d_in[27];
  const float* plk_b2 = (const float*)d_in[28];
  const float* sxy_w1 = (const float*)d_in[29];
  const float* sxy_b1 = (const float*)d_in[30];
  const float* sxy_w2 = (const float*)d_in[31];
  const float* sxy_b2 = (const float*)d_in[32];
  const float* gqn_g = (const float*)d_in[33];
  const float* gqn_b = (const float*)d_in[34];
  const float* gkn_g = (const float*)d_in[35];
  const float* gkn_b = (const float*)d_in[36];
  const float* wqg = (const float*)d_in[37];
  const float* bqg = (const float*)d_in[38];
  const float* wkg = (const float*)d_in[39];
  const float* bkg = (const float*)d_in[40];

  char* ws = (char*)d_ws;
  size_t off = 0;
  auto alloc = [&](size_t bytes) {
    size_t r = off;
    off += (bytes + 255) & ~(size_t)255;
    return r;
  };
  u16*   wpool   = (u16*)(ws + alloc((size_t)TOTW * 2));
  float* bkv     = (float*)(ws + alloc(1024 * 4));
  u16*   ffT     = (u16*)(ws + alloc((size_t)NF * 320 * 2));
  u16*   pos_h   = (u16*)(ws + alloc((size_t)NF * MD * 2));
  u16*   plk_h   = (u16*)(ws + alloc((size_t)NF * GHID * 2));
  u16*   sxy_h   = (u16*)(ws + alloc((size_t)NS * GHID * 2));
  u16*   pos     = (u16*)(ws + alloc((size_t)NF * MD * 2));
  u16*   feat_pre= (u16*)(ws + alloc((size_t)NF * MD * 2));
  u16*   satf_pre= (u16*)(ws + alloc((size_t)NS * MD * 2));
  u16*   satf    = (u16*)(ws + alloc((size_t)NS * MD * 2));
  u16*   q_embed = (u16*)(ws + alloc((size_t)NF * MD * 2));
  u16*   plk2    = (u16*)(ws + alloc((size_t)NF * GHID * 2));
  u16*   sxy2    = (u16*)(ws + alloc((size_t)NS * GHID * 2));
  u16*   Qaug    = (u16*)(ws + alloc((size_t)8 * NF * DA * 2));
  u16*   Kaug    = (u16*)(ws + alloc((size_t)8 * NS * DA * 2));
  u16*   VT      = (u16*)(ws + alloc((size_t)8 * HD * NS * 2));
  float* kk2     = (float*)(ws + alloc((size_t)NS * 4));
  u16*   Opart   = (u16*)(ws + alloc((size_t)NSPLIT * 8 * NF * 64 * 2));
  float* lbuf    = (float*)(ws + alloc((size_t)NSPLIT * 8 * NF * 4));
  // aliases (producer dead before alias written)
  u16* plk_ln = plk_h;
  u16* sgf    = sxy_h;

  dim3 b256(256);
  // L0: convert + ffT + silus + aug pad/kk2
  k_l0<<<dim3(13953), b256, 0, stream>>>(
      pos_w2, fa_w, sa_w, wq, wk, wv, plk_w2, sxy_w2, wqg, wkg, sat_tokens,
      wpool, bk, bv, bkv, front_feat, ffT,
      bev_xy, pos_w1, pos_b1, pos_h,
      plucker, plk_w1, plk_b1, plk_h,
      sat_xy, sxy_w1, sxy_b1, sxy_h,
      Qaug, Kaug, kk2);

  // L1 GEMMs (128x64 tiles, plain epilogues)
  GP gpos {pos_h, wpool + OFF_POSW2, pos_b2, pos, 512, 512, 4096, EPI_OUT, 0.f, nullptr, nullptr, 0};
  GP gfeat{ffT, wpool + OFF_FAW, fa_b, feat_pre, 320, 512, 4096, EPI_OUT, 0.f, nullptr, nullptr, 0};
  GP gsat {wpool + OFF_SATT, wpool + OFF_SAW, sa_b, satf_pre, 768, 512, 1024, EPI_OUT, 0.f, nullptr, nullptr, 0};
  GP ggq1 {plk_h, wpool + OFF_PLKW2, plk_b2, plk2, 128, 128, 4096, EPI_OUT, 0.f, nullptr, nullptr, 0};
  GP ggk1 {sxy_h, wpool + OFF_SXYW2, sxy_b2, sxy2, 128, 128, 1024, EPI_OUT, 0.f, nullptr, nullptr, 0};
  k_gemm_L1<<<dim3(656), b256, 0, stream>>>(gpos, gfeat, gsat, ggq1, ggk1);

  // LNs
  k_ln_all<<<dim3(2560), b256, 0, stream>>>(
      feat_pre, pos, fa_ln_g, fa_ln_b, qn_g, qn_b, q_embed,
      satf_pre, sa_ln_g, sa_ln_b, satf,
      plk2, sxy2, gqn_g, gqn_b, gkn_g, gkn_b, plk_ln, sgf);

  // L2 GEMMs with fused rope/VT/geo epilogues (64x64 tiles)
  GP gq  {q_embed, wpool + OFF_WQ, bq, nullptr, 512, 512, 4096, EPI_ROPE, 0.125f * L2E, bev_xy, Qaug, NF};
  GP gkv {satf, wpool + OFF_WKV, bkv, nullptr, 512, 1024, 1024, EPI_ROPE, 1.f, sat_xy, Kaug, NS};
  GP ggq2{plk_ln, wpool + OFF_WQG, bqg, nullptr, 128, 128, 4096, EPI_GEO, 0.25f * L2E, nullptr, Qaug, NF};
  GP ggk2{sgf, wpool + OFF_WKG, bkg, nullptr, 128, 128, 1024, EPI_GEO, 1.f, nullptr, Kaug, NS};
  k_gemm_L2<<<dim3(928), b256, 0, stream>>>(gq, gkv, ggq2, ggk2, VT);

  // flash (r9 staged version) + separate combine
  k_flash<<<dim3(NF / 64, 8, NSPLIT), b256, 0, stream>>>(Qaug, Kaug, VT, kk2, Opart, lbuf);
  k_combine<<<dim3(NF * MD / 4 / 256), b256, 0, stream>>>(Opart, lbuf, (float*)d_out);
}